// Round 11
// baseline (24.260 us; speedup 1.0000x reference)
//
#include <hip/hip_runtime.h>

#define NBINS 256
#define BPS   32     // blocks per sample -> 128*32 = 4096 blocks (16/CU -> 2 generations of 8)
#define NT    256    // threads per block (4 waves)
#define NCOPY 16     // histogram copies; 16 KB LDS -> 8 blocks/CU resident

typedef float floatx4 __attribute__((ext_vector_type(4)));  // native vec for nt-load

// ---------------- Kernel 1: per-block partial histograms ----------------
// ITER=6 -> 24 data VGPRs: the full load batch fits comfortably under the
// 64-VGPR cap of __launch_bounds__(NT,8), so all 6 loads stay in flight
// (no compiler register-reuse serialization). Conflict-free replicated
// histogram (copy = tid&15); two generations of resident blocks hide the
// DS/merge/store tail of generation 1 under generation 2's loads.
template<int N4>   // float4 elements per block (compile-time; 1536 here)
__global__ __launch_bounds__(NT, 8) void hist_kernel_t(const float* __restrict__ x,
                                                       unsigned int* __restrict__ phist,
                                                       float* __restrict__ out) {
    __shared__ unsigned int lh[NBINS * NCOPY];   // 16 KB
    const int tid  = threadIdx.x;
    const int copy = tid & (NCOPY - 1);

    if (blockIdx.x == 0 && tid == 0) out[0] = 0.0f;

    #pragma unroll
    for (int k = 0; k < NBINS * NCOPY / NT; ++k)
        lh[k * NT + tid] = 0u;

    constexpr int ITER = N4 / NT;                // 6
    const floatx4* src = (const floatx4*)x + (size_t)blockIdx.x * N4;

    floatx4 v[ITER];
    #pragma unroll
    for (int i = 0; i < ITER; ++i)
        v[i] = __builtin_nontemporal_load(&src[tid + i * NT]);

    __syncthreads();   // zeroing complete (loads already in flight)

    #pragma unroll
    for (int i = 0; i < ITER; ++i) {
        unsigned int i0 = (unsigned int)fminf(v[i].x * 256.0f, 255.0f);
        unsigned int i1 = (unsigned int)fminf(v[i].y * 256.0f, 255.0f);
        unsigned int i2 = (unsigned int)fminf(v[i].z * 256.0f, 255.0f);
        unsigned int i3 = (unsigned int)fminf(v[i].w * 256.0f, 255.0f);
        atomicAdd(&lh[(i0 << 4) | copy], 1u);
        atomicAdd(&lh[(i1 << 4) | copy], 1u);
        atomicAdd(&lh[(i2 << 4) | copy], 1u);
        atomicAdd(&lh[(i3 << 4) | copy], 1u);
    }
    __syncthreads();

    // merge: thread t owns bin t; rotate copy order to spread banks
    unsigned int s = 0;
    #pragma unroll
    for (int k = 0; k < NCOPY; ++k)
        s += lh[(tid << 4) | ((tid + k) & (NCOPY - 1))];
    phist[(size_t)blockIdx.x * NBINS + tid] = s;
}

// Generic fallback (runtime sizes) — simple loop version.
__global__ __launch_bounds__(NT) void hist_kernel_g(const float* __restrict__ x,
                                                    unsigned int* __restrict__ phist,
                                                    float* __restrict__ out,
                                                    int n_per_sample) {
    __shared__ unsigned int lh[NBINS * NCOPY];
    const int tid  = threadIdx.x;
    const int copy = tid & (NCOPY - 1);
    if (blockIdx.x == 0 && tid == 0) out[0] = 0.0f;
    for (int k = 0; k < NBINS * NCOPY / NT; ++k)
        lh[k * NT + tid] = 0u;
    __syncthreads();
    const int b     = blockIdx.x / BPS;
    const int blk   = blockIdx.x % BPS;
    const int chunk = n_per_sample / BPS;
    const float4* src = (const float4*)(x + (size_t)b * n_per_sample
                                          + (size_t)blk * chunk);
    const int n4 = chunk >> 2;
    for (int i = tid; i < n4; i += NT) {
        float4 v = src[i];
        unsigned int i0 = (unsigned int)fminf(v.x * 256.0f, 255.0f);
        unsigned int i1 = (unsigned int)fminf(v.y * 256.0f, 255.0f);
        unsigned int i2 = (unsigned int)fminf(v.z * 256.0f, 255.0f);
        unsigned int i3 = (unsigned int)fminf(v.w * 256.0f, 255.0f);
        atomicAdd(&lh[(i0 << 4) | copy], 1u);
        atomicAdd(&lh[(i1 << 4) | copy], 1u);
        atomicAdd(&lh[(i2 << 4) | copy], 1u);
        atomicAdd(&lh[(i3 << 4) | copy], 1u);
    }
    __syncthreads();
    unsigned int s = 0;
    #pragma unroll
    for (int k = 0; k < NCOPY; ++k)
        s += lh[(tid << 4) | ((tid + k) & (NCOPY - 1))];
    phist[(size_t)blockIdx.x * NBINS + tid] = s;
}

// ---------------- Kernel 2: sum partials -> entropy -> MSE contribution ----------------
__global__ __launch_bounds__(NBINS) void entropy_kernel(const unsigned int* __restrict__ phist,
                                                        const float* __restrict__ target,
                                                        float* __restrict__ out,
                                                        float inv_n, float inv_b) {
    const int b   = blockIdx.x;
    const int tid = threadIdx.x;

    const unsigned int* base = phist + (size_t)b * BPS * NBINS;
    unsigned int h = 0;
    #pragma unroll
    for (int k = 0; k < BPS; ++k) h += base[k * NBINS + tid];

    float t = 0.0f;
    if (h > 0u) {
        float p = (float)h * inv_n;
        t = -p * log2f(p);
    }
    #pragma unroll
    for (int off = 32; off > 0; off >>= 1) t += __shfl_down(t, off, 64);
    __shared__ float ws[NBINS / 64];
    if ((tid & 63) == 0) ws[tid >> 6] = t;
    __syncthreads();
    if (tid == 0) {
        float ent = 0.0f;
        #pragma unroll
        for (int w = 0; w < NBINS / 64; ++w) ent += ws[w];
        float d = ent - target[b];
        atomicAdd(out, d * d * inv_b);
    }
}

extern "C" void kernel_launch(void* const* d_in, const int* in_sizes, int n_in,
                              void* d_out, int out_size, void* d_ws, size_t ws_size,
                              hipStream_t stream) {
    const float* x      = (const float*)d_in[0];
    const float* target = (const float*)d_in[1];
    float* out          = (float*)d_out;

    const int B = in_sizes[1];                 // 128
    const int N = in_sizes[0] / B;             // 196608

    unsigned int* phist = (unsigned int*)d_ws; // B*BPS*NBINS uints (4 MB)

    if (N == 196608) {
        constexpr int N4 = (196608 / BPS) / 4; // 1536 float4 per block
        hist_kernel_t<N4><<<B * BPS, NT, 0, stream>>>(x, phist, out);
    } else {
        hist_kernel_g<<<B * BPS, NT, 0, stream>>>(x, phist, out, N);
    }
    entropy_kernel<<<B, NBINS, 0, stream>>>(phist, target, out,
                                            1.0f / (float)N, 1.0f / (float)B);
}

// Round 12
// 22.892 us; speedup vs baseline: 1.0598x; 1.0598x over previous
//
#include <hip/hip_runtime.h>

#define NBINS 256
#define BPS   16     // blocks per sample -> 2048 blocks (16/CU total, 8 resident -> 2 generations)
#define NT    256    // threads per block (4 waves)
#define NCOPY 16     // histogram copies; 16 KB LDS -> 8 blocks/CU resident

typedef float floatx4 __attribute__((ext_vector_type(4)));  // native vec for nt-load

// ---------------- Kernel 1: per-block partial histograms ----------------
// R10 best config: ITER=12, NCOPY=16 conflict-free replicated histogram,
// 8 resident blocks/CU with two generations (gen 2's loads hide gen 1's
// DS/merge/store tail). copy = tid&15 -> bank = copy + 16*(bin&1): lanes
// sharing a copy are 16 apart -> typically 2-way aliasing (free).
template<int N4>   // float4 elements per block (compile-time; 3072 here)
__global__ __launch_bounds__(NT, 8) void hist_kernel_t(const float* __restrict__ x,
                                                       unsigned int* __restrict__ phist,
                                                       float* __restrict__ out) {
    __shared__ unsigned int lh[NBINS * NCOPY];   // 16 KB
    const int tid  = threadIdx.x;
    const int copy = tid & (NCOPY - 1);

    if (blockIdx.x == 0 && tid == 0) out[0] = 0.0f;

    #pragma unroll
    for (int k = 0; k < NBINS * NCOPY / NT; ++k)
        lh[k * NT + tid] = 0u;

    constexpr int ITER = N4 / NT;                // 12
    const floatx4* src = (const floatx4*)x + (size_t)blockIdx.x * N4;

    floatx4 v[ITER];
    #pragma unroll
    for (int i = 0; i < ITER; ++i)
        v[i] = __builtin_nontemporal_load(&src[tid + i * NT]);

    __syncthreads();   // zeroing complete (loads already in flight)

    #pragma unroll
    for (int i = 0; i < ITER; ++i) {
        unsigned int i0 = (unsigned int)fminf(v[i].x * 256.0f, 255.0f);
        unsigned int i1 = (unsigned int)fminf(v[i].y * 256.0f, 255.0f);
        unsigned int i2 = (unsigned int)fminf(v[i].z * 256.0f, 255.0f);
        unsigned int i3 = (unsigned int)fminf(v[i].w * 256.0f, 255.0f);
        atomicAdd(&lh[(i0 << 4) | copy], 1u);
        atomicAdd(&lh[(i1 << 4) | copy], 1u);
        atomicAdd(&lh[(i2 << 4) | copy], 1u);
        atomicAdd(&lh[(i3 << 4) | copy], 1u);
    }
    __syncthreads();

    // merge: thread t owns bin t; rotate copy order to spread banks
    unsigned int s = 0;
    #pragma unroll
    for (int k = 0; k < NCOPY; ++k)
        s += lh[(tid << 4) | ((tid + k) & (NCOPY - 1))];
    phist[(size_t)blockIdx.x * NBINS + tid] = s;
}

// Generic fallback (runtime sizes) — simple loop version.
__global__ __launch_bounds__(NT) void hist_kernel_g(const float* __restrict__ x,
                                                    unsigned int* __restrict__ phist,
                                                    float* __restrict__ out,
                                                    int n_per_sample) {
    __shared__ unsigned int lh[NBINS * NCOPY];
    const int tid  = threadIdx.x;
    const int copy = tid & (NCOPY - 1);
    if (blockIdx.x == 0 && tid == 0) out[0] = 0.0f;
    for (int k = 0; k < NBINS * NCOPY / NT; ++k)
        lh[k * NT + tid] = 0u;
    __syncthreads();
    const int b     = blockIdx.x / BPS;
    const int blk   = blockIdx.x % BPS;
    const int chunk = n_per_sample / BPS;
    const float4* src = (const float4*)(x + (size_t)b * n_per_sample
                                          + (size_t)blk * chunk);
    const int n4 = chunk >> 2;
    for (int i = tid; i < n4; i += NT) {
        float4 v = src[i];
        unsigned int i0 = (unsigned int)fminf(v.x * 256.0f, 255.0f);
        unsigned int i1 = (unsigned int)fminf(v.y * 256.0f, 255.0f);
        unsigned int i2 = (unsigned int)fminf(v.z * 256.0f, 255.0f);
        unsigned int i3 = (unsigned int)fminf(v.w * 256.0f, 255.0f);
        atomicAdd(&lh[(i0 << 4) | copy], 1u);
        atomicAdd(&lh[(i1 << 4) | copy], 1u);
        atomicAdd(&lh[(i2 << 4) | copy], 1u);
        atomicAdd(&lh[(i3 << 4) | copy], 1u);
    }
    __syncthreads();
    unsigned int s = 0;
    #pragma unroll
    for (int k = 0; k < NCOPY; ++k)
        s += lh[(tid << 4) | ((tid + k) & (NCOPY - 1))];
    phist[(size_t)blockIdx.x * NBINS + tid] = s;
}

// ---------------- Kernel 2: sum partials -> entropy -> MSE contribution ----------------
// Partials for sample b loaded as 4x uint4 per thread (vectorized, all
// independent) instead of 16 scalar loads -> shorter latency chain.
__global__ __launch_bounds__(NBINS) void entropy_kernel(const unsigned int* __restrict__ phist,
                                                        const float* __restrict__ target,
                                                        float* __restrict__ out,
                                                        float inv_n, float inv_b) {
    const int b   = blockIdx.x;
    const int tid = threadIdx.x;

    const unsigned int* base = phist + (size_t)b * BPS * NBINS;
    uint4 pv[BPS / 4];
    #pragma unroll
    for (int k = 0; k < BPS / 4; ++k) {
        // thread t reads bin t of partials 4k..4k+3; partial j's bin t is at
        // j*NBINS + t. Transpose access: load 4 consecutive partials' bin t
        // as one uint4 is NOT contiguous; instead vectorize over bins:
        // thread t loads bins 4t..4t+3 of partial k? That changes ownership.
        // Keep ownership (bin t) and just batch the scalar loads:
        pv[k].x = base[(4 * k + 0) * NBINS + tid];
        pv[k].y = base[(4 * k + 1) * NBINS + tid];
        pv[k].z = base[(4 * k + 2) * NBINS + tid];
        pv[k].w = base[(4 * k + 3) * NBINS + tid];
    }
    unsigned int h = 0;
    #pragma unroll
    for (int k = 0; k < BPS / 4; ++k) h += pv[k].x + pv[k].y + pv[k].z + pv[k].w;

    float t = 0.0f;
    if (h > 0u) {
        float p = (float)h * inv_n;
        t = -p * log2f(p);
    }
    #pragma unroll
    for (int off = 32; off > 0; off >>= 1) t += __shfl_down(t, off, 64);
    __shared__ float ws[NBINS / 64];
    if ((tid & 63) == 0) ws[tid >> 6] = t;
    __syncthreads();
    if (tid == 0) {
        float ent = 0.0f;
        #pragma unroll
        for (int w = 0; w < NBINS / 64; ++w) ent += ws[w];
        float d = ent - target[b];
        atomicAdd(out, d * d * inv_b);
    }
}

extern "C" void kernel_launch(void* const* d_in, const int* in_sizes, int n_in,
                              void* d_out, int out_size, void* d_ws, size_t ws_size,
                              hipStream_t stream) {
    const float* x      = (const float*)d_in[0];
    const float* target = (const float*)d_in[1];
    float* out          = (float*)d_out;

    const int B = in_sizes[1];                 // 128
    const int N = in_sizes[0] / B;             // 196608

    unsigned int* phist = (unsigned int*)d_ws; // B*BPS*NBINS uints (2 MB)

    if (N == 196608) {
        constexpr int N4 = (196608 / BPS) / 4; // 3072 float4 per block
        hist_kernel_t<N4><<<B * BPS, NT, 0, stream>>>(x, phist, out);
    } else {
        hist_kernel_g<<<B * BPS, NT, 0, stream>>>(x, phist, out, N);
    }
    entropy_kernel<<<B, NBINS, 0, stream>>>(phist, target, out,
                                            1.0f / (float)N, 1.0f / (float)B);
}